// Round 24
// baseline (218.436 us; speedup 1.0000x reference)
//
#include <hip/hip_runtime.h>
#include <hip/hip_bf16.h>

#define KA 512
#define DD 1024
#define LMBDA_C 1000.0f
#define T_ITER 11

typedef short bf16x8 __attribute__((ext_vector_type(8)));   // 8 bf16 (4 VGPRs)
typedef float f32x4 __attribute__((ext_vector_type(4)));

__device__ __forceinline__ float bf2f(unsigned short v) {
  return __uint_as_float(((unsigned)v) << 16);
}

// ---------------------------------------------------------------------------
// Fused: dtype detect (scan 8192 16-bit words of input A; f32 data decodes to
// huge bf16-interpretations w.h.p., P(miss) ~ 0.52^8192 ~ 0) + eval convert
// + joint spectral max. One block of 512.
__global__ void k_prep(const void* Ain, const void* ea_in, const void* eb_in,
                       float* eaf, float* ebf, float* smax, float* maxbuf) {
  __shared__ float red[512];
  const int t = threadIdx.x;
  const ushort4* u4 = (const ushort4*)Ain;
  float m = 0.f;
  for (int i = t; i < 2048; i += 512) {            // 8192 words
    const ushort4 v = u4[i];
    float f0 = fabsf(bf2f(v.x)), f1 = fabsf(bf2f(v.y));
    float f2 = fabsf(bf2f(v.z)), f3 = fabsf(bf2f(v.w));
    if (!isnan(f0)) m = fmaxf(m, f0);
    if (!isnan(f1)) m = fmaxf(m, f1);
    if (!isnan(f2)) m = fmaxf(m, f2);
    if (!isnan(f3)) m = fmaxf(m, f3);
  }
  red[t] = m;
  __syncthreads();
  for (int s = 256; s > 0; s >>= 1) {
    if (t < s) red[t] = fmaxf(red[t], red[t + s]);
    __syncthreads();
  }
  const float mx = red[0];
  const bool isbf = (mx < 100.f);
  if (t == 0) maxbuf[0] = mx;
  __syncthreads();
  const float a = isbf ? bf2f(((const unsigned short*)ea_in)[t])
                       : ((const float*)ea_in)[t];
  const float b = isbf ? bf2f(((const unsigned short*)eb_in)[t])
                       : ((const float*)eb_in)[t];
  eaf[t] = a;
  ebf[t] = b;
  red[t] = fmaxf(a, b);
  __syncthreads();
  for (int s = 256; s > 0; s >>= 1) {
    if (t < s) red[t] = fmaxf(red[t], red[t + s]);
    __syncthreads();
  }
  if (t == 0) smax[0] = red[0];
}

// ---------------------------------------------------------------------------
// bf16 path: MFMA gram. G = L^T * Rm via mfma_f32_16x16x32_bf16 (bf16
// products are exact in f32 — numerically equivalent to the f32 gram modulo
// sum order). Verified layouts (m89/m120): A[m=lane&15][k=quad*8+j],
// B[k=quad*8+j][n=lane&15], D[row=quad*4+reg][col=lane&15].
// 64x64 tile/block, 4 waves; wave w owns rows w*16..w*16+16 (4 col-tiles).
// LDS: k-transposed tiles (row stride 40 shorts = 80 B: 16B-aligned b128
// frag reads, conflict-free; staging writes 2-way max).
// z=0: G_a=A^T A, z=1: G_b=B^T B, z=2: M=B^T A (R_bot = M^T read by k_pcg).
#define LTS 40
__global__ __launch_bounds__(256) void k_gram_mfma(const void* __restrict__ Av,
    const void* __restrict__ Bv, float* __restrict__ Gfin,
    const float* __restrict__ maxbuf) {
  if (maxbuf[0] >= 100.f) return;   // f32 data: handled by k_gram fallback
  __shared__ __align__(16) unsigned short Lt[64][LTS];
  __shared__ __align__(16) unsigned short Bt[64][LTS];
  const int z = blockIdx.z;
  const unsigned short *L, *Rm;
  int off;
  if (z == 0)      { L = (const unsigned short*)Av; Rm = L; off = 0; }
  else if (z == 1) { L = (const unsigned short*)Bv; Rm = L; off = 262144; }
  else             { L = (const unsigned short*)Bv;
                     Rm = (const unsigned short*)Av; off = 524288; }
  float* out = Gfin + off;
  const int r0 = blockIdx.y * 64, c0 = blockIdx.x * 64;
  const int t = threadIdx.x;
  const int lane = t & 63, w = t >> 6;
  const int quad = lane >> 4, l16 = lane & 15;
  // staging map: kk = t&31 (k-row in stage), mm = (t>>5)*8 (col group)
  const int kk = t & 31;
  const int mm = (t >> 5) * 8;

  f32x4 acc0 = {0.f, 0.f, 0.f, 0.f};
  f32x4 acc1 = acc0, acc2 = acc0, acc3 = acc0;

  for (int k0 = 0; k0 < DD; k0 += 32) {
    const ushort4 la = *(const ushort4*)(L + (k0 + kk) * KA + r0 + mm);
    const ushort4 lb = *(const ushort4*)(L + (k0 + kk) * KA + r0 + mm + 4);
    const ushort4 ra = *(const ushort4*)(Rm + (k0 + kk) * KA + c0 + mm);
    const ushort4 rb = *(const ushort4*)(Rm + (k0 + kk) * KA + c0 + mm + 4);
    __syncthreads();                 // previous stage's frag reads complete
    Lt[mm + 0][kk] = la.x; Lt[mm + 1][kk] = la.y;
    Lt[mm + 2][kk] = la.z; Lt[mm + 3][kk] = la.w;
    Lt[mm + 4][kk] = lb.x; Lt[mm + 5][kk] = lb.y;
    Lt[mm + 6][kk] = lb.z; Lt[mm + 7][kk] = lb.w;
    Bt[mm + 0][kk] = ra.x; Bt[mm + 1][kk] = ra.y;
    Bt[mm + 2][kk] = ra.z; Bt[mm + 3][kk] = ra.w;
    Bt[mm + 4][kk] = rb.x; Bt[mm + 5][kk] = rb.y;
    Bt[mm + 6][kk] = rb.z; Bt[mm + 7][kk] = rb.w;
    __syncthreads();
    const bf16x8 af = *(const bf16x8*)&Lt[w * 16 + l16][quad * 8];
    const bf16x8 bf0 = *(const bf16x8*)&Bt[ 0 + l16][quad * 8];
    const bf16x8 bf1 = *(const bf16x8*)&Bt[16 + l16][quad * 8];
    const bf16x8 bf2 = *(const bf16x8*)&Bt[32 + l16][quad * 8];
    const bf16x8 bf3 = *(const bf16x8*)&Bt[48 + l16][quad * 8];
    acc0 = __builtin_amdgcn_mfma_f32_16x16x32_bf16(af, bf0, acc0, 0, 0, 0);
    acc1 = __builtin_amdgcn_mfma_f32_16x16x32_bf16(af, bf1, acc1, 0, 0, 0);
    acc2 = __builtin_amdgcn_mfma_f32_16x16x32_bf16(af, bf2, acc2, 0, 0, 0);
    acc3 = __builtin_amdgcn_mfma_f32_16x16x32_bf16(af, bf3, acc3, 0, 0, 0);
  }
  const int orow = r0 + w * 16 + quad * 4;
#pragma unroll
  for (int r = 0; r < 4; ++r) {
    float* op = out + (orow + r) * KA + c0 + l16;
    op[0]  = acc0[r];
    op[16] = acc1[r];
    op[32] = acc2[r];
    op[48] = acc3[r];
  }
}

// ---------------------------------------------------------------------------
// f32 fallback path (predicated): R12-proven 64x64 tile, k-split x2.
// z=0: G_a, z=1: G_b, z=2: M=B^T A, z=3: A^T B (unused by pcg; harmless)
__global__ __launch_bounds__(256) void k_gram(const void* __restrict__ A,
    const void* __restrict__ B, float* __restrict__ Gfin,
    float* __restrict__ Gp0, const float* __restrict__ maxbuf) {
  if (maxbuf[0] < 100.f) return;    // bf16 data: handled by k_gram_mfma
  __shared__ float sL[16][68];
  __shared__ float sR[16][68];
  const int z2 = blockIdx.z;
  const int h = z2 & 1, z = z2 >> 1;
  const void *L, *Rm;
  int off;
  if (z == 0)      { L = A; Rm = A; off = 0; }
  else if (z == 1) { L = B; Rm = B; off = 262144; }
  else if (z == 2) { L = B; Rm = A; off = 524288; }
  else             { L = A; Rm = B; off = 786432; }
  float* out = (h ? Gfin : Gp0) + off;
  const int r0 = blockIdx.y * 64, c0 = blockIdx.x * 64;
  const int tx = threadIdx.x, ty = threadIdx.y;
  const int t = ty * 16 + tx;
  const int Ld = t >> 4;
  const int Lc = (t & 15) * 4;
  const int kbeg = h * 512;
  float acc[4][4] = {};
  for (int k0 = kbeg; k0 < kbeg + 512; k0 += 16) {
    *(float4*)&sL[Ld][Lc] = *(const float4*)((const float*)L +
                                             (k0 + Ld) * KA + r0 + Lc);
    *(float4*)&sR[Ld][Lc] = *(const float4*)((const float*)Rm +
                                             (k0 + Ld) * KA + c0 + Lc);
    __syncthreads();
#pragma unroll
    for (int d2 = 0; d2 < 16; ++d2) {
      const float4 av = *(const float4*)&sL[d2][ty * 4];
      const float4 bv = *(const float4*)&sR[d2][tx * 4];
      acc[0][0] = fmaf(av.x, bv.x, acc[0][0]); acc[0][1] = fmaf(av.x, bv.y, acc[0][1]);
      acc[0][2] = fmaf(av.x, bv.z, acc[0][2]); acc[0][3] = fmaf(av.x, bv.w, acc[0][3]);
      acc[1][0] = fmaf(av.y, bv.x, acc[1][0]); acc[1][1] = fmaf(av.y, bv.y, acc[1][1]);
      acc[1][2] = fmaf(av.y, bv.z, acc[1][2]); acc[1][3] = fmaf(av.y, bv.w, acc[1][3]);
      acc[2][0] = fmaf(av.z, bv.x, acc[2][0]); acc[2][1] = fmaf(av.z, bv.y, acc[2][1]);
      acc[2][2] = fmaf(av.z, bv.z, acc[2][2]); acc[2][3] = fmaf(av.z, bv.w, acc[2][3]);
      acc[3][0] = fmaf(av.w, bv.x, acc[3][0]); acc[3][1] = fmaf(av.w, bv.y, acc[3][1]);
      acc[3][2] = fmaf(av.w, bv.z, acc[3][2]); acc[3][3] = fmaf(av.w, bv.w, acc[3][3]);
    }
    __syncthreads();
  }
#pragma unroll
  for (int u = 0; u < 4; ++u) {
    const float4 o = make_float4(acc[u][0], acc[u][1], acc[u][2], acc[u][3]);
    *(float4*)(out + (r0 + ty * 4 + u) * KA + c0 + tx * 4) = o;
  }
}

// Gfin += Gp0 (f32 path only)
__global__ void k_combine(float* __restrict__ Gfin, const float* __restrict__ Gp0,
                          const float* __restrict__ maxbuf) {
  if (maxbuf[0] < 100.f) return;    // bf16 path: no partials
  const int i = blockIdx.x * 256 + threadIdx.x;
  float4* f4 = (float4*)Gfin;
  const float4 a = f4[i], b = ((const float4*)Gp0)[i];
  f4[i] = make_float4(a.x + b.x, a.y + b.y, a.z + b.z, a.w + b.w);
}

// ---------------------------------------------------------------------------
__device__ __forceinline__ float rowreduce1(float v, float* red, int tid) {
#pragma unroll
  for (int off = 32; off > 0; off >>= 1) v += __shfl_down(v, off, 64);
  if ((tid & 63) == 0) red[tid >> 6] = v;
  __syncthreads();
  const int r = (tid >> 7) * 2;
  return red[r] + red[r + 1];
}

#define ACC16(pp, g)                                                         \
  a0.x = fmaf(p0.pp, g.x, a0.x); a0.y = fmaf(p0.pp, g.y, a0.y);              \
  a0.z = fmaf(p0.pp, g.z, a0.z); a0.w = fmaf(p0.pp, g.w, a0.w);              \
  a1.x = fmaf(p1.pp, g.x, a1.x); a1.y = fmaf(p1.pp, g.y, a1.y);              \
  a1.z = fmaf(p1.pp, g.z, a1.z); a1.w = fmaf(p1.pp, g.w, a1.w);              \
  a2.x = fmaf(p2.pp, g.x, a2.x); a2.y = fmaf(p2.pp, g.y, a2.y);              \
  a2.z = fmaf(p2.pp, g.z, a2.z); a2.w = fmaf(p2.pp, g.w, a2.w);              \
  a3.x = fmaf(p3.pp, g.x, a3.x); a3.y = fmaf(p3.pp, g.y, a3.y);              \
  a3.z = fmaf(p3.pp, g.z, a3.z); a3.w = fmaf(p3.pp, g.w, a3.w);

// Whole PCG loop fused (R13 hot loop, unchanged except rhs source):
// dir0 rhs = M[row][:] (float4); dir1 rhs = M^T -> 4 scalar gathers at init.
// Measured R20/R23: 131.5-133us, VALUBusy ~43%, Occ 21% (1 block/CU), FETCH
// 12MB -> per-CU L2-ingest bound (1MB G-stream/iter/CU ~18.7K cyc vs 8.2K VALU).
__global__ __launch_bounds__(512, 2) void k_pcg(
    const float* __restrict__ G_a, const float* __restrict__ G_b,
    const float* __restrict__ M, const float* __restrict__ ea,
    const float* __restrict__ eb, const float* __restrict__ smax,
    const float* __restrict__ maxbuf, void* __restrict__ out) {
  __shared__ float p_s[4][KA];
  __shared__ float qp_s[4][4][KA];
  __shared__ float redbuf[4][8];

  const int tid = threadIdx.x;
  const int b = blockIdx.x;
  const int rb = b * 4;
  const int dir = rb >> 9;
  const float* __restrict__ G = dir ? G_b : G_a;

  const int ks = tid >> 7;
  const int j0 = (tid & 127) << 2;
  const int urow = tid >> 7;
  const int uc = (tid & 127) << 2;
  const int growu = rb + urow;
  const int rowl = growu & (KA - 1);

  const float s = smax[0];
  const float e1 = (dir ? ea[rowl] : eb[rowl]) / s;
  const float q1 = 1.f / (e1 * e1 + 1.f);
  const float p1i = e1 * q1;
  float4 w4;
  {
    const float* e2p = dir ? eb : ea;
    const float4 e2 = *(const float4*)(e2p + uc);
    const float vx = e2.x / s, vy = e2.y / s, vz = e2.z / s, vw = e2.w / s;
    const float qx = 1.f / (vx * vx + 1.f), qy = 1.f / (vy * vy + 1.f);
    const float qz = 1.f / (vz * vz + 1.f), qw = 1.f / (vw * vw + 1.f);
    float dre, dim;
    dre = p1i - vx * qx; dim = q1 - qx; w4.x = LMBDA_C * (dre * dre + dim * dim);
    dre = p1i - vy * qy; dim = q1 - qy; w4.y = LMBDA_C * (dre * dre + dim * dim);
    dre = p1i - vz * qz; dim = q1 - qz; w4.z = LMBDA_C * (dre * dre + dim * dim);
    dre = p1i - vw * qw; dim = q1 - qw; w4.w = LMBDA_C * (dre * dre + dim * dim);
  }
  float4 di4;
  di4.x = 1.f / (G[(uc + 0) * KA + uc + 0] + w4.x);
  di4.y = 1.f / (G[(uc + 1) * KA + uc + 1] + w4.y);
  di4.z = 1.f / (G[(uc + 2) * KA + uc + 2] + w4.z);
  di4.w = 1.f / (G[(uc + 3) * KA + uc + 3] + w4.w);
  float4 r4;
  if (dir == 0) {
    r4 = *(const float4*)(M + growu * KA + uc);
  } else {                      // rhs = (B^T A)^T: gather M column rowl
    r4.x = M[(uc + 0) * KA + rowl];
    r4.y = M[(uc + 1) * KA + rowl];
    r4.z = M[(uc + 2) * KA + rowl];
    r4.w = M[(uc + 3) * KA + rowl];
  }
  float4 x4 = make_float4(0.f, 0.f, 0.f, 0.f);
  float4 z4 = make_float4(r4.x * di4.x, r4.y * di4.y, r4.z * di4.z, r4.w * di4.w);
  *(float4*)&p_s[urow][uc] = z4;
  float rho = rowreduce1(r4.x * z4.x + r4.y * z4.y + r4.z * z4.z + r4.w * z4.w,
                         redbuf[3], tid);

  for (int it = 0; it < T_ITER; ++it) {
    {
      float4 a0 = make_float4(0.f, 0.f, 0.f, 0.f);
      float4 a1 = a0, a2 = a0, a3 = a0;
      const int kbeg = ks << 7;
      const float* __restrict__ Gq = G + kbeg * KA + j0;
      float4 g0 = *(const float4*)(Gq + 0 * KA);
      float4 g1 = *(const float4*)(Gq + 1 * KA);
      float4 g2 = *(const float4*)(Gq + 2 * KA);
      float4 g3 = *(const float4*)(Gq + 3 * KA);
      float4 n0 = *(const float4*)(Gq + 4 * KA);
      float4 n1 = *(const float4*)(Gq + 5 * KA);
      float4 n2 = *(const float4*)(Gq + 6 * KA);
      float4 n3 = *(const float4*)(Gq + 7 * KA);
#pragma unroll 2
      for (int kc = 0; kc < 128; kc += 4) {
        const float* __restrict__ Gm = Gq + (kc + 8) * KA;
        const float4 m0 = *(const float4*)(Gm + 0 * KA);
        const float4 m1 = *(const float4*)(Gm + 1 * KA);
        const float4 m2 = *(const float4*)(Gm + 2 * KA);
        const float4 m3 = *(const float4*)(Gm + 3 * KA);
        const int k = kbeg + kc;
        const float4 p0 = *(const float4*)&p_s[0][k];
        const float4 p1 = *(const float4*)&p_s[1][k];
        const float4 p2 = *(const float4*)&p_s[2][k];
        const float4 p3 = *(const float4*)&p_s[3][k];
        ACC16(x, g0)
        ACC16(y, g1)
        ACC16(z, g2)
        ACC16(w, g3)
        g0 = n0; g1 = n1; g2 = n2; g3 = n3;
        n0 = m0; n1 = m1; n2 = m2; n3 = m3;
      }
      *(float4*)&qp_s[ks][0][j0] = a0;
      *(float4*)&qp_s[ks][1][j0] = a1;
      *(float4*)&qp_s[ks][2][j0] = a2;
      *(float4*)&qp_s[ks][3][j0] = a3;
    }
    __syncthreads();
    const float4 p4 = *(const float4*)&p_s[urow][uc];
    const float4 qa = *(const float4*)&qp_s[0][urow][uc];
    const float4 qb = *(const float4*)&qp_s[1][urow][uc];
    const float4 qc = *(const float4*)&qp_s[2][urow][uc];
    const float4 qd = *(const float4*)&qp_s[3][urow][uc];
    float4 q;
    q.x = qa.x + qb.x + qc.x + qd.x + w4.x * p4.x;
    q.y = qa.y + qb.y + qc.y + qd.y + w4.y * p4.y;
    q.z = qa.z + qb.z + qc.z + qd.z + w4.z * p4.z;
    q.w = qa.w + qb.w + qc.w + qd.w + w4.w * p4.w;
    const float pq = rowreduce1(
        p4.x * q.x + p4.y * q.y + p4.z * q.z + p4.w * q.w,
        redbuf[it & 1], tid);
    const float alpha = (pq != 0.f) ? (rho / pq) : 0.f;
    x4.x = fmaf(alpha, p4.x, x4.x); x4.y = fmaf(alpha, p4.y, x4.y);
    x4.z = fmaf(alpha, p4.z, x4.z); x4.w = fmaf(alpha, p4.w, x4.w);
    r4.x = fmaf(-alpha, q.x, r4.x); r4.y = fmaf(-alpha, q.y, r4.y);
    r4.z = fmaf(-alpha, q.z, r4.z); r4.w = fmaf(-alpha, q.w, r4.w);
    z4 = make_float4(r4.x * di4.x, r4.y * di4.y, r4.z * di4.z, r4.w * di4.w);
    const float rhon = rowreduce1(
        r4.x * z4.x + r4.y * z4.y + r4.z * z4.z + r4.w * z4.w,
        redbuf[2 + (it & 1)], tid);
    const float beta = (rho != 0.f) ? (rhon / rho) : 0.f;
    rho = rhon;
    float4 pn;
    pn.x = fmaf(beta, p4.x, z4.x); pn.y = fmaf(beta, p4.y, z4.y);
    pn.z = fmaf(beta, p4.z, z4.z); pn.w = fmaf(beta, p4.w, z4.w);
    *(float4*)&p_s[urow][uc] = pn;
    __syncthreads();
  }

  const bool isbf = (maxbuf[0] < 100.f);
  const int o = growu * KA + uc;
  if (isbf) {
    __hip_bfloat16* ob = (__hip_bfloat16*)out;
    ob[o + 0] = __float2bfloat16(x4.x);
    ob[o + 1] = __float2bfloat16(x4.y);
    ob[o + 2] = __float2bfloat16(x4.z);
    ob[o + 3] = __float2bfloat16(x4.w);
  } else {
    *(float4*)((float*)out + o) = x4;
  }
}

// ---------------------------------------------------------------------------
extern "C" void kernel_launch(void* const* d_in, const int* in_sizes, int n_in,
                              void* d_out, int out_size, void* d_ws, size_t ws_size,
                              hipStream_t stream) {
  const void* Ain = d_in[0];   // sdescr_a [1024,512]
  const void* Bin = d_in[1];   // sdescr_b [1024,512]
  const void* Ein_a = d_in[2]; // evals_a [512]
  const void* Ein_b = d_in[3]; // evals_b [512]

  float* ws = (float*)d_ws;
  float* Gfin  = ws;              // 1048576 = [G_a | G_b | M | (f32-path A^T B)]
  float* Gp0   = Gfin + 1048576;  // 1048576 (f32-path k-half partial)
  float* eaf   = Gp0 + 1048576;   // 512
  float* ebf   = eaf + 512;       // 512
  float* maxbuf= ebf + 512;       // 1
  float* smax  = maxbuf + 1;      // 1

  float* G_a = Gfin;
  float* G_b = Gfin + 262144;
  float* M   = Gfin + 524288;

  k_prep<<<1, 512, 0, stream>>>(Ain, Ein_a, Ein_b, eaf, ebf, smax, maxbuf);
  k_gram_mfma<<<dim3(8, 8, 3), 256, 0, stream>>>(Ain, Bin, Gfin, maxbuf);
  k_gram<<<dim3(8, 8, 8), dim3(16, 16), 0, stream>>>(Ain, Bin, Gfin, Gp0, maxbuf);
  k_combine<<<1024, 256, 0, stream>>>(Gfin, Gp0, maxbuf);
  k_pcg<<<256, 512, 0, stream>>>(G_a, G_b, M, eaf, ebf, smax, maxbuf, d_out);
}